// Round 1
// baseline (457.452 us; speedup 1.0000x reference)
//
#include <hip/hip_runtime.h>

// FWHT of 16384 rows x 4096 fp32, times scalar scale.
// One wave (64 threads) per row. Element index i (12 bits) split as:
//   c = i & 3 (float4 component), t = (i>>2) & 63 (lane), j = i >> 8 (reg idx).
// Phase 1: butterflies on bits {0,1,8,9,10,11} in registers.
// LDS transpose (write b32 conflict-free, read b128 bank-even) moves
// bits 2..7 into registers. Phase 2: butterflies on bits {2..7}. Store.

#define SJ 68     // LDS word stride between j-blocks (64 + 4 pad, mult of 4)
#define SC 1096   // LDS word stride between c-blocks (16*68=1088 + 8, mult of 4)
#define LDS_WORDS (3 * SC + 15 * SJ + 64)  // 3288 + 1020 + 64 = 4372 words

__global__ __launch_bounds__(64) void fwht_kernel(
    const float* __restrict__ x, const float* __restrict__ scale,
    float* __restrict__ out) {
  __shared__ float lds[LDS_WORDS];
  const int t = threadIdx.x;          // 0..63
  const int row = blockIdx.x;         // 0..16383
  const float* xr = x + (size_t)row * 4096;
  float* outr = out + (size_t)row * 4096;

  // ---- load: v[j][c] = x[j*256 + 4t + c] (fully coalesced float4) ----
  float v[16][4];
#pragma unroll
  for (int j = 0; j < 16; ++j) {
    const float4 f = *reinterpret_cast<const float4*>(xr + j * 256 + 4 * t);
    v[j][0] = f.x; v[j][1] = f.y; v[j][2] = f.z; v[j][3] = f.w;
  }

  // ---- phase 1a: butterflies on c bits (i-bits 0,1) ----
#pragma unroll
  for (int j = 0; j < 16; ++j) {
    // bit 0: pairs (0,1),(2,3)
    {
      float a = v[j][0], b = v[j][1];
      v[j][0] = a + b; v[j][1] = a - b;
      float a2 = v[j][2], b2 = v[j][3];
      v[j][2] = a2 + b2; v[j][3] = a2 - b2;
    }
    // bit 1: pairs (0,2),(1,3)
    {
      float a = v[j][0], b = v[j][2];
      v[j][0] = a + b; v[j][2] = a - b;
      float a2 = v[j][1], b2 = v[j][3];
      v[j][1] = a2 + b2; v[j][3] = a2 - b2;
    }
  }

  // ---- phase 1b: butterflies on j bits (i-bits 8..11) ----
#pragma unroll
  for (int bit = 0; bit < 4; ++bit) {
    const int mask = 1 << bit;
#pragma unroll
    for (int j = 0; j < 16; ++j) {
      if (!(j & mask)) {
        const int k = j | mask;
#pragma unroll
        for (int c = 0; c < 4; ++c) {
          float a = v[j][c], b = v[k][c];
          v[j][c] = a + b; v[k][c] = a - b;
        }
      }
    }
  }

  // ---- transpose via LDS: element i=j*256+4t+c stored at t + j*SJ + c*SC ----
#pragma unroll
  for (int j = 0; j < 16; ++j) {
#pragma unroll
    for (int c = 0; c < 4; ++c) {
      lds[t + j * SJ + c * SC] = v[j][c];
    }
  }

  __syncthreads();

  // lane t' now owns jp = t>>2 (i-bits 8..11), cp = t&3 (i-bits 0,1);
  // reads w[m] = elem[jp*256 + 4m + cp] = lds[m + jp*SJ + cp*SC], m=0..63.
  const int jp = t >> 2, cp = t & 3;
  const int rbase = jp * SJ + cp * SC;
  float w[64];
#pragma unroll
  for (int k = 0; k < 16; ++k) {
    const float4 f = *reinterpret_cast<const float4*>(&lds[rbase + 4 * k]);
    w[4 * k + 0] = f.x; w[4 * k + 1] = f.y;
    w[4 * k + 2] = f.z; w[4 * k + 3] = f.w;
  }

  // ---- phase 2: butterflies on m bits (i-bits 2..7) ----
#pragma unroll
  for (int bit = 0; bit < 6; ++bit) {
    const int mask = 1 << bit;
#pragma unroll
    for (int m = 0; m < 64; ++m) {
      if (!(m & mask)) {
        const int k = m | mask;
        float a = w[m], b = w[k];
        w[m] = a + b; w[k] = a - b;
      }
    }
  }

  // ---- scale + store: out[jp*256 + 4m + cp] = w[m]*s ----
  const float s = scale[0];
  float* ob = outr + jp * 256 + cp;
#pragma unroll
  for (int m = 0; m < 64; ++m) {
    ob[4 * m] = w[m] * s;
  }
}

extern "C" void kernel_launch(void* const* d_in, const int* in_sizes, int n_in,
                              void* d_out, int out_size, void* d_ws, size_t ws_size,
                              hipStream_t stream) {
  const float* x = (const float*)d_in[0];
  const float* scale = (const float*)d_in[1];
  float* out = (float*)d_out;
  const int rows = 16384;  // 16384 * 4096 == in_sizes[0]
  fwht_kernel<<<rows, 64, 0, stream>>>(x, scale, out);
}